// Round 6
// baseline (453.265 us; speedup 1.0000x reference)
//
#include <hip/hip_runtime.h>
#include <hip/hip_bf16.h>
#include <stdint.h>

typedef __attribute__((ext_vector_type(8))) short short8;
typedef __attribute__((ext_vector_type(4))) float f32x4;

#define NSLICE 8
#define SLICE_J 1024
#define CHUNKS 16   // SLICE_J / 64
#define L2E 1.44269504f
#define L2E5 0.288539008f   // 0.2 * log2(e)

static __device__ __forceinline__ short f2bf(float f) {
    unsigned int u = __float_as_uint(f);
    u += 0x7fffu + ((u >> 16) & 1u);   // RNE
    return (short)(u >> 16);
}

// pack two f32 -> one int holding 2 bf16 (v_cvt_pk_bf16_f32 on gfx950)
static __device__ __forceinline__ int pk2(float a, float b) {
    float2 f2 = make_float2(a, b);
    __hip_bfloat162 h = __float22bfloat162_rn(f2);
    return *reinterpret_cast<int*>(&h);
}

// ---------------- Phase 1: Wh = h@W -> e1, e2 (fp32), whT in B-fragment tiles --
// whT layout (shorts): tile(=j>>6)*4096 + ((n>>4)*2 + frag)*512 + qk*128 + (n&15)*8 + t
__global__ __launch_bounds__(256)
void gat_wh(const float* __restrict__ h, const float* __restrict__ W,
            const float* __restrict__ a, short* __restrict__ whT,
            float* __restrict__ e1, float* __restrict__ e2)
{
    const int lane = threadIdx.x & 63;
    const int wave = threadIdx.x >> 6;
    const int row0 = blockIdx.x * 8 + wave * 2;   // 1024 blocks x 4 waves x 2 rows

    float acc[2] = {0.f, 0.f};
#pragma unroll 8
    for (int c = 0; c < 512; ++c) {
        const float wv = W[c * 64 + lane];          // coalesced
#pragma unroll
        for (int r = 0; r < 2; ++r)                 // h index wave-uniform -> s_load
            acc[r] += h[(size_t)(row0 + r) * 512 + c] * wv;
    }

    const float a1v = a[lane];
    const float a2v = a[64 + lane];
    const int f    = lane >> 4;
    const int r16n = lane & 15;
#pragma unroll
    for (int r = 0; r < 2; ++r) {
        float p1 = acc[r] * a1v;
        float p2 = acc[r] * a2v;
#pragma unroll
        for (int off = 32; off; off >>= 1) {
            p1 += __shfl_xor(p1, off);
            p2 += __shfl_xor(p2, off);
        }
        if (lane == 0) { e1[row0 + r] = p1; e2[row0 + r] = p2; }
        const int j = row0 + r;
        const int kin = j & 63;
        const int frag = (kin >> 5) & 1, qk = (kin >> 3) & 3, t = kin & 7;
        whT[(size_t)(j >> 6) * 4096 + (f * 2 + frag) * 512 + qk * 128 + r16n * 8 + t]
            = f2bf(acc[r]);
    }
}

// ---------------- Phase 2: masked factored-exp + P@Wh --------------------------
// P_ij = adj * exp(lrelu(e1_i+e2_j)) = adj * max(exp(e1_i)exp(e2_j),
//                                               exp(.2 e1_i)exp(.2 e2_j))
// -> zero transcendentals per element.
__global__ __launch_bounds__(256)
void gat_attn(const int* __restrict__ adj, const short* __restrict__ whT,
              const float* __restrict__ e1, const float* __restrict__ e2,
              float* __restrict__ lpart, float* __restrict__ opart)
{
    __shared__ __align__(16) float2 sB[SLICE_J];   // (b1, b5) per column j
    const int bid = blockIdx.x;
    const int s   = bid & (NSLICE - 1);
    const int rb  = bid >> 3;
    const int tid = threadIdx.x;

    // stage b1=exp(e2), b5=exp(0.2 e2) for the slice (4 j's per thread)
    {
        const float4 v = *reinterpret_cast<const float4*>(e2 + s * SLICE_J + tid * 4);
        float4 lo, hi;
        lo.x = __builtin_amdgcn_exp2f(v.x * L2E);  lo.y = __builtin_amdgcn_exp2f(v.x * L2E5);
        lo.z = __builtin_amdgcn_exp2f(v.y * L2E);  lo.w = __builtin_amdgcn_exp2f(v.y * L2E5);
        hi.x = __builtin_amdgcn_exp2f(v.z * L2E);  hi.y = __builtin_amdgcn_exp2f(v.z * L2E5);
        hi.z = __builtin_amdgcn_exp2f(v.w * L2E);  hi.w = __builtin_amdgcn_exp2f(v.w * L2E5);
        reinterpret_cast<float4*>(sB)[tid * 2]     = lo;
        reinterpret_cast<float4*>(sB)[tid * 2 + 1] = hi;
    }
    __syncthreads();

    const int lane = tid & 63;
    const int wave = tid >> 6;
    const int quad = lane >> 4;
    const int r16  = lane & 15;
    const int rowBase = rb * 64 + wave * 16;
    const int row  = rowBase + r16;
    const float e1v = e1[row];
    const float a1 = __builtin_amdgcn_exp2f(e1v * L2E);
    const float a5 = __builtin_amdgcn_exp2f(e1v * L2E5);
    const size_t adjRow = (size_t)row * 8192 + (size_t)s * SLICE_J;

    float ls0 = 0.f, ls1 = 0.f, ls2 = 0.f, ls3 = 0.f;
    f32x4 acc[4];
#pragma unroll
    for (int ff = 0; ff < 4; ++ff) acc[ff] = (f32x4){0.f, 0.f, 0.f, 0.f};

    const int jq = quad * 8;
    // prefetch chunk 0 adj (A-fragment layout: m=r16, k=quad*8+t, +32 for frag1)
    int4 A0 = *reinterpret_cast<const int4*>(adj + adjRow + jq);
    int4 A1 = *reinterpret_cast<const int4*>(adj + adjRow + jq + 4);
    int4 A2 = *reinterpret_cast<const int4*>(adj + adjRow + jq + 32);
    int4 A3 = *reinterpret_cast<const int4*>(adj + adjRow + jq + 36);

    for (int ch = 0; ch < CHUNKS; ++ch) {
        const int chn = (ch + 1) & (CHUNKS - 1);     // wraps; last iter re-reads ch0 (L2 hit)
        const size_t nbase = adjRow + chn * 64 + jq;
        const int4 N0 = *reinterpret_cast<const int4*>(adj + nbase);
        const int4 N1 = *reinterpret_cast<const int4*>(adj + nbase + 4);
        const int4 N2 = *reinterpret_cast<const int4*>(adj + nbase + 32);
        const int4 N3 = *reinterpret_cast<const int4*>(adj + nbase + 36);

        const int j0 = ch * 64 + jq;
        const float4 P0 = *reinterpret_cast<const float4*>(&sB[j0]);
        const float4 P1 = *reinterpret_cast<const float4*>(&sB[j0 + 2]);
        const float4 P2 = *reinterpret_cast<const float4*>(&sB[j0 + 4]);
        const float4 P3 = *reinterpret_cast<const float4*>(&sB[j0 + 6]);
        const float4 P4 = *reinterpret_cast<const float4*>(&sB[j0 + 32]);
        const float4 P5 = *reinterpret_cast<const float4*>(&sB[j0 + 34]);
        const float4 P6 = *reinterpret_cast<const float4*>(&sB[j0 + 36]);
        const float4 P7 = *reinterpret_cast<const float4*>(&sB[j0 + 38]);

        // w = adj ? max(a1*b1, a5*b5) : 0
        float w0  = (A0.x > 0) ? fmaxf(a1 * P0.x, a5 * P0.y) : 0.f;
        float w1  = (A0.y > 0) ? fmaxf(a1 * P0.z, a5 * P0.w) : 0.f;
        float w2  = (A0.z > 0) ? fmaxf(a1 * P1.x, a5 * P1.y) : 0.f;
        float w3  = (A0.w > 0) ? fmaxf(a1 * P1.z, a5 * P1.w) : 0.f;
        float w4  = (A1.x > 0) ? fmaxf(a1 * P2.x, a5 * P2.y) : 0.f;
        float w5  = (A1.y > 0) ? fmaxf(a1 * P2.z, a5 * P2.w) : 0.f;
        float w6  = (A1.z > 0) ? fmaxf(a1 * P3.x, a5 * P3.y) : 0.f;
        float w7  = (A1.w > 0) ? fmaxf(a1 * P3.z, a5 * P3.w) : 0.f;
        float w8  = (A2.x > 0) ? fmaxf(a1 * P4.x, a5 * P4.y) : 0.f;
        float w9  = (A2.y > 0) ? fmaxf(a1 * P4.z, a5 * P4.w) : 0.f;
        float w10 = (A2.z > 0) ? fmaxf(a1 * P5.x, a5 * P5.y) : 0.f;
        float w11 = (A2.w > 0) ? fmaxf(a1 * P5.z, a5 * P5.w) : 0.f;
        float w12 = (A3.x > 0) ? fmaxf(a1 * P6.x, a5 * P6.y) : 0.f;
        float w13 = (A3.y > 0) ? fmaxf(a1 * P6.z, a5 * P6.w) : 0.f;
        float w14 = (A3.z > 0) ? fmaxf(a1 * P7.x, a5 * P7.y) : 0.f;
        float w15 = (A3.w > 0) ? fmaxf(a1 * P7.z, a5 * P7.w) : 0.f;

        ls0 += w0 + w1 + w2 + w3;
        ls1 += w4 + w5 + w6 + w7;
        ls2 += w8 + w9 + w10 + w11;
        ls3 += w12 + w13 + w14 + w15;

        union { int4 i; short8 s; } U0, U1;
        U0.i = make_int4(pk2(w0, w1),  pk2(w2, w3),  pk2(w4, w5),  pk2(w6, w7));
        U1.i = make_int4(pk2(w8, w9),  pk2(w10, w11), pk2(w12, w13), pk2(w14, w15));

        // B-fragment loads: whT pre-permuted -> 64 lanes x 16 B contiguous
        const short* wtile = whT + (size_t)(s * 16 + ch) * 4096 + lane * 8;
#pragma unroll
        for (int ff = 0; ff < 4; ++ff) {
            const short8 b0 = *reinterpret_cast<const short8*>(wtile + (ff * 2 + 0) * 512);
            const short8 b1 = *reinterpret_cast<const short8*>(wtile + (ff * 2 + 1) * 512);
            acc[ff] = __builtin_amdgcn_mfma_f32_16x16x32_bf16(U0.s, b0, acc[ff], 0, 0, 0);
            acc[ff] = __builtin_amdgcn_mfma_f32_16x16x32_bf16(U1.s, b1, acc[ff], 0, 0, 0);
        }

        A0 = N0; A1 = N1; A2 = N2; A3 = N3;
    }

    float lsum = (ls0 + ls1) + (ls2 + ls3);
    lsum += __shfl_xor(lsum, 16);
    lsum += __shfl_xor(lsum, 32);
    if (lane < 16) lpart[s * 8192 + rowBase + lane] = lsum;

#pragma unroll
    for (int ff = 0; ff < 4; ++ff) {
#pragma unroll
        for (int rg = 0; rg < 4; ++rg) {
            const int orow = rowBase + quad * 4 + rg;
            const int ocol = ff * 16 + r16;
            opart[((size_t)s * 8192 + orow) * 64 + ocol] = acc[ff][rg];
        }
    }
}

// ---------------- Phase 3: merge slice partials, normalize, ELU ----------------
__global__ __launch_bounds__(256)
void gat_combine(const float* __restrict__ lpart, const float* __restrict__ opart,
                 float* __restrict__ out)
{
    const int gid = blockIdx.x * 256 + threadIdx.x;
    const int row = gid >> 6;
    const int f   = gid & 63;

    float lsum = 0.f, osum = 0.f;
#pragma unroll
    for (int s = 0; s < NSLICE; ++s) {
        lsum += lpart[s * 8192 + row];
        osum += opart[((size_t)s * 8192 + row) * 64 + f];
    }
    const float v = osum / lsum;
    out[gid] = (v > 0.f) ? v : (__expf(v) - 1.f);
}

extern "C" void kernel_launch(void* const* d_in, const int* in_sizes, int n_in,
                              void* d_out, int out_size, void* d_ws, size_t ws_size,
                              hipStream_t stream) {
    const float* h   = (const float*)d_in[0];
    const int*   adj = (const int*)d_in[1];
    const float* W   = (const float*)d_in[2];
    const float* a   = (const float*)d_in[3];
    float* out = (float*)d_out;

    char* ws = (char*)d_ws;
    short* whT   = (short*)ws;                                   // 1 MB
    float* e1    = (float*)(ws + (1u << 20));                    // 32 KB
    float* e2    = (float*)(ws + (1u << 20) + (32u << 10));      // 32 KB
    float* lpart = (float*)(ws + (1u << 20) + (64u << 10));      // 256 KB
    float* opart = (float*)(ws + (2u << 20));                    // 16 MB

    gat_wh<<<1024, 256, 0, stream>>>(h, W, a, whT, e1, e2);
    gat_attn<<<128 * NSLICE, 256, 0, stream>>>(adj, whT, e1, e2, lpart, opart);
    gat_combine<<<out_size / 256, 256, 0, stream>>>(lpart, opart, out);
}

// Round 7
// 449.366 us; speedup vs baseline: 1.0087x; 1.0087x over previous
//
#include <hip/hip_runtime.h>
#include <hip/hip_bf16.h>
#include <stdint.h>

typedef __attribute__((ext_vector_type(8))) short short8;
typedef __attribute__((ext_vector_type(4))) float f32x4;

#define NSLICE 8
#define SLICE_J 1024
#define CHUNKS 16   // SLICE_J / 64
#define L2E 1.44269504f
#define L2E5 0.288539008f   // 0.2 * log2(e)

static __device__ __forceinline__ short f2bf(float f) {
    unsigned int u = __float_as_uint(f);
    u += 0x7fffu + ((u >> 16) & 1u);   // RNE
    return (short)(u >> 16);
}

// pack two f32 -> one int holding 2 bf16 (v_cvt_pk_bf16_f32 on gfx950)
static __device__ __forceinline__ int pk2(float a, float b) {
    float2 f2 = make_float2(a, b);
    __hip_bfloat162 h = __float22bfloat162_rn(f2);
    return *reinterpret_cast<int*>(&h);
}

// ---------------- Phase 0: compress adj (int32 0/1) -> 1-bit mask --------------
// Perfectly coalesced sequential read of the 256 MB adj (the only cold HBM
// stream in the pipeline); writes 8 MB bitmask (bit k of byte g = adj[g*8+k]).
__global__ __launch_bounds__(256)
void gat_pack(const int* __restrict__ adj, unsigned char* __restrict__ bm)
{
    const int g = blockIdx.x * 256 + threadIdx.x;
    const int4 a0 = reinterpret_cast<const int4*>(adj)[(size_t)g * 2];
    const int4 a1 = reinterpret_cast<const int4*>(adj)[(size_t)g * 2 + 1];
    unsigned int m = 0;
    m |= (a0.x > 0) ? 1u   : 0u;
    m |= (a0.y > 0) ? 2u   : 0u;
    m |= (a0.z > 0) ? 4u   : 0u;
    m |= (a0.w > 0) ? 8u   : 0u;
    m |= (a1.x > 0) ? 16u  : 0u;
    m |= (a1.y > 0) ? 32u  : 0u;
    m |= (a1.z > 0) ? 64u  : 0u;
    m |= (a1.w > 0) ? 128u : 0u;
    bm[g] = (unsigned char)m;
}

// ---------------- Phase 1: Wh = h@W -> e1, e2 (fp32), whT in B-fragment tiles --
// whT layout (shorts): tile(=j>>6)*4096 + ((n>>4)*2 + frag)*512 + qk*128 + (n&15)*8 + t
__global__ __launch_bounds__(256)
void gat_wh(const float* __restrict__ h, const float* __restrict__ W,
            const float* __restrict__ a, short* __restrict__ whT,
            float* __restrict__ e1, float* __restrict__ e2)
{
    const int lane = threadIdx.x & 63;
    const int wave = threadIdx.x >> 6;
    const int row0 = blockIdx.x * 8 + wave * 2;   // 1024 blocks x 4 waves x 2 rows

    float acc[2] = {0.f, 0.f};
#pragma unroll 8
    for (int c = 0; c < 512; ++c) {
        const float wv = W[c * 64 + lane];          // coalesced
#pragma unroll
        for (int r = 0; r < 2; ++r)                 // h index wave-uniform -> s_load
            acc[r] += h[(size_t)(row0 + r) * 512 + c] * wv;
    }

    const float a1v = a[lane];
    const float a2v = a[64 + lane];
    const int f    = lane >> 4;
    const int r16n = lane & 15;
#pragma unroll
    for (int r = 0; r < 2; ++r) {
        float p1 = acc[r] * a1v;
        float p2 = acc[r] * a2v;
#pragma unroll
        for (int off = 32; off; off >>= 1) {
            p1 += __shfl_xor(p1, off);
            p2 += __shfl_xor(p2, off);
        }
        if (lane == 0) { e1[row0 + r] = p1; e2[row0 + r] = p2; }
        const int j = row0 + r;
        const int kin = j & 63;
        const int frag = (kin >> 5) & 1, qk = (kin >> 3) & 3, t = kin & 7;
        whT[(size_t)(j >> 6) * 4096 + (f * 2 + frag) * 512 + qk * 128 + r16n * 8 + t]
            = f2bf(acc[r]);
    }
}

// ---------------- Phase 2: masked factored-exp + P@Wh --------------------------
// P_ij = adj * max(exp(e1_i)exp(e2_j), exp(.2 e1_i)exp(.2 e2_j)); mask from the
// L2-resident bitmask (one uint2 broadcast per wave-chunk) -> adj HBM traffic 0.
__global__ __launch_bounds__(256)
void gat_attn(const unsigned char* __restrict__ bm, const short* __restrict__ whT,
              const float* __restrict__ e1, const float* __restrict__ e2,
              float* __restrict__ lpart, float* __restrict__ opart)
{
    __shared__ __align__(16) float2 sB[SLICE_J];   // (b1, b5) per column j
    const int bid = blockIdx.x;
    const int s   = bid & (NSLICE - 1);
    const int rb  = bid >> 3;
    const int tid = threadIdx.x;

    // stage b1=exp(e2), b5=exp(0.2 e2) for the slice (4 j's per thread)
    {
        const float4 v = *reinterpret_cast<const float4*>(e2 + s * SLICE_J + tid * 4);
        float4 lo, hi;
        lo.x = __builtin_amdgcn_exp2f(v.x * L2E);  lo.y = __builtin_amdgcn_exp2f(v.x * L2E5);
        lo.z = __builtin_amdgcn_exp2f(v.y * L2E);  lo.w = __builtin_amdgcn_exp2f(v.y * L2E5);
        hi.x = __builtin_amdgcn_exp2f(v.z * L2E);  hi.y = __builtin_amdgcn_exp2f(v.z * L2E5);
        hi.z = __builtin_amdgcn_exp2f(v.w * L2E);  hi.w = __builtin_amdgcn_exp2f(v.w * L2E5);
        reinterpret_cast<float4*>(sB)[tid * 2]     = lo;
        reinterpret_cast<float4*>(sB)[tid * 2 + 1] = hi;
    }
    __syncthreads();

    const int lane = tid & 63;
    const int wave = tid >> 6;
    const int quad = lane >> 4;
    const int r16  = lane & 15;
    const int rowBase = rb * 64 + wave * 16;
    const int row  = rowBase + r16;
    const float e1v = e1[row];
    const float a1 = __builtin_amdgcn_exp2f(e1v * L2E);
    const float a5 = __builtin_amdgcn_exp2f(e1v * L2E5);
    // bitmask row pointer: row*1024 bytes + slice offset
    const unsigned char* bmRow = bm + (size_t)row * 1024 + s * 128;
    const int qs = quad * 8;

    float ls0 = 0.f, ls1 = 0.f, ls2 = 0.f, ls3 = 0.f;
    f32x4 acc[4];
#pragma unroll
    for (int ff = 0; ff < 4; ++ff) acc[ff] = (f32x4){0.f, 0.f, 0.f, 0.f};

    for (int ch = 0; ch < CHUNKS; ++ch) {
        // 64-col mask for this row/chunk: M.x = cols 0..31, M.y = cols 32..63
        const uint2 M = *reinterpret_cast<const uint2*>(bmRow + ch * 8);
        const unsigned int lo = M.x >> qs;   // bit t -> col quad*8+t      (frag0)
        const unsigned int hi = M.y >> qs;   // bit t -> col 32+quad*8+t   (frag1)

        const int j0 = ch * 64 + qs;
        const float4 P0 = *reinterpret_cast<const float4*>(&sB[j0]);
        const float4 P1 = *reinterpret_cast<const float4*>(&sB[j0 + 2]);
        const float4 P2 = *reinterpret_cast<const float4*>(&sB[j0 + 4]);
        const float4 P3 = *reinterpret_cast<const float4*>(&sB[j0 + 6]);
        const float4 P4 = *reinterpret_cast<const float4*>(&sB[j0 + 32]);
        const float4 P5 = *reinterpret_cast<const float4*>(&sB[j0 + 34]);
        const float4 P6 = *reinterpret_cast<const float4*>(&sB[j0 + 36]);
        const float4 P7 = *reinterpret_cast<const float4*>(&sB[j0 + 38]);

        // w = bit ? max(a1*b1, a5*b5) : 0
        float w0  = (lo & 1u)   ? fmaxf(a1 * P0.x, a5 * P0.y) : 0.f;
        float w1  = (lo & 2u)   ? fmaxf(a1 * P0.z, a5 * P0.w) : 0.f;
        float w2  = (lo & 4u)   ? fmaxf(a1 * P1.x, a5 * P1.y) : 0.f;
        float w3  = (lo & 8u)   ? fmaxf(a1 * P1.z, a5 * P1.w) : 0.f;
        float w4  = (lo & 16u)  ? fmaxf(a1 * P2.x, a5 * P2.y) : 0.f;
        float w5  = (lo & 32u)  ? fmaxf(a1 * P2.z, a5 * P2.w) : 0.f;
        float w6  = (lo & 64u)  ? fmaxf(a1 * P3.x, a5 * P3.y) : 0.f;
        float w7  = (lo & 128u) ? fmaxf(a1 * P3.z, a5 * P3.w) : 0.f;
        float w8  = (hi & 1u)   ? fmaxf(a1 * P4.x, a5 * P4.y) : 0.f;
        float w9  = (hi & 2u)   ? fmaxf(a1 * P4.z, a5 * P4.w) : 0.f;
        float w10 = (hi & 4u)   ? fmaxf(a1 * P5.x, a5 * P5.y) : 0.f;
        float w11 = (hi & 8u)   ? fmaxf(a1 * P5.z, a5 * P5.w) : 0.f;
        float w12 = (hi & 16u)  ? fmaxf(a1 * P6.x, a5 * P6.y) : 0.f;
        float w13 = (hi & 32u)  ? fmaxf(a1 * P6.z, a5 * P6.w) : 0.f;
        float w14 = (hi & 64u)  ? fmaxf(a1 * P7.x, a5 * P7.y) : 0.f;
        float w15 = (hi & 128u) ? fmaxf(a1 * P7.z, a5 * P7.w) : 0.f;

        ls0 += w0 + w1 + w2 + w3;
        ls1 += w4 + w5 + w6 + w7;
        ls2 += w8 + w9 + w10 + w11;
        ls3 += w12 + w13 + w14 + w15;

        union { int4 i; short8 s; } U0, U1;
        U0.i = make_int4(pk2(w0, w1),  pk2(w2, w3),   pk2(w4, w5),   pk2(w6, w7));
        U1.i = make_int4(pk2(w8, w9),  pk2(w10, w11), pk2(w12, w13), pk2(w14, w15));

        // B-fragment loads: whT pre-permuted -> 64 lanes x 16 B contiguous (L2)
        const short* wtile = whT + (size_t)(s * 16 + ch) * 4096 + lane * 8;
#pragma unroll
        for (int ff = 0; ff < 4; ++ff) {
            const short8 b0 = *reinterpret_cast<const short8*>(wtile + (ff * 2 + 0) * 512);
            const short8 b1 = *reinterpret_cast<const short8*>(wtile + (ff * 2 + 1) * 512);
            acc[ff] = __builtin_amdgcn_mfma_f32_16x16x32_bf16(U0.s, b0, acc[ff], 0, 0, 0);
            acc[ff] = __builtin_amdgcn_mfma_f32_16x16x32_bf16(U1.s, b1, acc[ff], 0, 0, 0);
        }
    }

    float lsum = (ls0 + ls1) + (ls2 + ls3);
    lsum += __shfl_xor(lsum, 16);
    lsum += __shfl_xor(lsum, 32);
    if (lane < 16) lpart[s * 8192 + rowBase + lane] = lsum;

#pragma unroll
    for (int ff = 0; ff < 4; ++ff) {
#pragma unroll
        for (int rg = 0; rg < 4; ++rg) {
            const int orow = rowBase + quad * 4 + rg;
            const int ocol = ff * 16 + r16;
            opart[((size_t)s * 8192 + orow) * 64 + ocol] = acc[ff][rg];
        }
    }
}

// ---------------- Phase 3: merge slice partials, normalize, ELU ----------------
__global__ __launch_bounds__(256)
void gat_combine(const float* __restrict__ lpart, const float* __restrict__ opart,
                 float* __restrict__ out)
{
    const int gid = blockIdx.x * 256 + threadIdx.x;
    const int row = gid >> 6;
    const int f   = gid & 63;

    float lsum = 0.f, osum = 0.f;
#pragma unroll
    for (int s = 0; s < NSLICE; ++s) {
        lsum += lpart[s * 8192 + row];
        osum += opart[((size_t)s * 8192 + row) * 64 + f];
    }
    const float v = osum / lsum;
    out[gid] = (v > 0.f) ? v : (__expf(v) - 1.f);
}

extern "C" void kernel_launch(void* const* d_in, const int* in_sizes, int n_in,
                              void* d_out, int out_size, void* d_ws, size_t ws_size,
                              hipStream_t stream) {
    const float* h   = (const float*)d_in[0];
    const int*   adj = (const int*)d_in[1];
    const float* W   = (const float*)d_in[2];
    const float* a   = (const float*)d_in[3];
    float* out = (float*)d_out;

    char* ws = (char*)d_ws;
    short* whT   = (short*)ws;                                   // 1 MB
    float* e1    = (float*)(ws + (1u << 20));                    // 32 KB
    float* e2    = (float*)(ws + (1u << 20) + (32u << 10));      // 32 KB
    float* lpart = (float*)(ws + (1u << 20) + (64u << 10));      // 256 KB
    float* opart = (float*)(ws + (2u << 20));                    // 16 MB
    unsigned char* bmask = (unsigned char*)(ws + (32u << 20));   // 8 MB

    gat_pack<<<32768, 256, 0, stream>>>(adj, bmask);
    gat_wh<<<1024, 256, 0, stream>>>(h, W, a, whT, e1, e2);
    gat_attn<<<128 * NSLICE, 256, 0, stream>>>(bmask, whT, e1, e2, lpart, opart);
    gat_combine<<<out_size / 256, 256, 0, stream>>>(lpart, opart, out);
}